// Round 12
// baseline (492.823 us; speedup 1.0000x reference)
//
#include <hip/hip_runtime.h>
#include <math.h>

// Fused CNN classifier: conv(1->8,3x3,s2,p1)+ReLU -> conv(8->16,3x3,s2,p1)+ReLU
//                       -> FC(784->1) -> softplus+0.001 -> 1-exp(-r) -> clip
// B=65536 images of 1x28x28 fp32.
//
// R12: occupancy via launch_bounds, with VGPR already fitting. Session-wide
// pattern: measured occupancy tracks the __launch_bounds__ 2nd arg (4->~40%
// R6/7/8/11, 6->63% R10), NOT the resource caps. R11 is latency-bound 11x
// above compute floor (1284 cy/img vs ~110) with only 3.2 waves/SIMD. R11's
// VGPR allocation is EXACTLY 64 = 512/8, and LDS 18.4KB allows 8 blocks/CU,
// so 8 waves/EU is resource-feasible TODAY. Single delta vs R11:
// __launch_bounds__(256, 8). Everything else identical (no-simg direct-
// global conv1 taps, SSA-only locals, barrier-free wave-private sz1).
// Predicted: occ 40->70-85%, dur 137.6->75-95us, VGPR stays 64, WRITE
// stays ~0.5MB. Spill signature (VGPR<64 + WRITE>>10MB) => revert to 4 and
// batch-2-images instead. Occ up + dur flat => shared-pipe stall, revert
// conv1 to trimmed-LDS staging.

typedef short bf16x8 __attribute__((ext_vector_type(8)));
typedef float f32x4  __attribute__((ext_vector_type(4)));

#define NBLOCKS 4096
#define Z1_RS 19                    // z1 row stride in 16B slots (odd!)
#define Z1_SLOTS (15 * Z1_RS)       // 285 slots per image

static __device__ __forceinline__ short f2bf(float f) {
    union { float f; unsigned u; } v; v.f = f;
    unsigned r = v.u + 0x7FFF + ((v.u >> 16) & 1);   // RNE (no NaN inputs)
    return (short)(r >> 16);
}

// One conv1 channel pair (CA, CA+1): 9-tap FMA + ReLU + pack to 2xbf16.
#define CONV1_PAIR(CA, PKDST) do {                                          \
    const float* wa_ = &W1[(CA) * 9];                                       \
    const float* wc_ = &W1[((CA) + 1) * 9];                                 \
    float za_ = b1[(CA)], zc_ = b1[(CA) + 1];                               \
    za_ = fmaf(t0, wa_[0], za_); zc_ = fmaf(t0, wc_[0], zc_);               \
    za_ = fmaf(t1, wa_[1], za_); zc_ = fmaf(t1, wc_[1], zc_);               \
    za_ = fmaf(t2, wa_[2], za_); zc_ = fmaf(t2, wc_[2], zc_);               \
    za_ = fmaf(t3, wa_[3], za_); zc_ = fmaf(t3, wc_[3], zc_);               \
    za_ = fmaf(t4, wa_[4], za_); zc_ = fmaf(t4, wc_[4], zc_);               \
    za_ = fmaf(t5, wa_[5], za_); zc_ = fmaf(t5, wc_[5], zc_);               \
    za_ = fmaf(t6, wa_[6], za_); zc_ = fmaf(t6, wc_[6], zc_);               \
    za_ = fmaf(t7, wa_[7], za_); zc_ = fmaf(t7, wc_[7], zc_);               \
    za_ = fmaf(t8, wa_[8], za_); zc_ = fmaf(t8, wc_[8], zc_);               \
    za_ = fmaxf(za_, 0.f);       zc_ = fmaxf(zc_, 0.f);                     \
    asm("v_cvt_pk_bf16_f32 %0, %1, %2" : "=v"(PKDST) : "v"(za_), "v"(zc_)); \
} while (0)

// One conv1 output position, taps read DIRECTLY from global image xi.
// Output pos (py,px) reads input rows 2py-1..2py+1, cols 2px-1..2px+1;
// row -1 / col -1 are pad-zeros: clamp the address, zero via 0/1 masks.
#define CONV1_STEP(I, STORE_COND) do {                                        \
    int p_ = (I) * 64 + lane; if (p_ > 195) p_ = 195;                         \
    int py_ = p_ / 14, px_ = p_ - py_ * 14;                                   \
    int r1_ = py_ * 56;                 /* (2py)*28   */                      \
    int r0_ = r1_ - 28; if (r0_ < 0) r0_ = 0;                                 \
    int r2_ = r1_ + 28;                                                       \
    int c1_ = px_ * 2;                                                        \
    int c0_ = c1_ - 1; if (c0_ < 0) c0_ = 0;                                  \
    float mt_  = (py_ > 0) ? 1.f : 0.f;                                       \
    float ml_  = (px_ > 0) ? 1.f : 0.f;                                       \
    float mtl_ = mt_ * ml_;                                                   \
    float2 a12 = *(const float2*)(xi + r0_ + c1_);   /* 8B-aligned */         \
    float  a0  = xi[r0_ + c0_];                                               \
    float2 b45 = *(const float2*)(xi + r1_ + c1_);                            \
    float  b3  = xi[r1_ + c0_];                                               \
    float2 c78 = *(const float2*)(xi + r2_ + c1_);                            \
    float  c6  = xi[r2_ + c0_];                                               \
    float t0 = a0 * mtl_, t1 = a12.x * mt_, t2 = a12.y * mt_;                 \
    float t3 = b3 * ml_,  t4 = b45.x,       t5 = b45.y;                       \
    float t6 = c6 * ml_,  t7 = c78.x,       t8 = c78.y;                       \
    asm volatile("" : "+v"(t0), "+v"(t1), "+v"(t2), "+v"(t3), "+v"(t4),       \
                      "+v"(t5), "+v"(t6), "+v"(t7), "+v"(t8));                \
    unsigned pk0_, pk1_, pk2_, pk3_;                                          \
    CONV1_PAIR(0, pk0_);                                                      \
    CONV1_PAIR(2, pk1_);                                                      \
    CONV1_PAIR(4, pk2_);                                                      \
    CONV1_PAIR(6, pk3_);                                                      \
    int zoff_ = ((py_ + 1) * Z1_RS + px_ + 1) * 16;                           \
    if (STORE_COND)                                                           \
        *(uint4*)(z1b + zoff_) = make_uint4(pk0_, pk1_, pk2_, pk3_);          \
} while (0)

__global__ __launch_bounds__(256, 8) void fused_cnn_mfma(
    const float* __restrict__ x,
    const float* __restrict__ W1, const float* __restrict__ b1,
    const float* __restrict__ W2, const float* __restrict__ b2,
    const float* __restrict__ Wfc, const float* __restrict__ bfc,
    float* __restrict__ out, int nimg)
{
    __shared__ bf16x8 sz1[4][Z1_SLOTS];                   // 18240 B only

    const int tid  = threadIdx.x;
    const int w    = tid >> 6;       // wave id = image slot (wave-private LDS)
    const int lane = tid & 63;
    const int hi   = lane >> 4;
    const int lo   = lane & 15;

    // ---------------- one-time setup (all wave-private, no barrier) --------
    {
        bf16x8 zz = {0,0,0,0,0,0,0,0};
        for (int i = lane; i < Z1_SLOTS; i += 64) sz1[w][i] = zz;
    }

    // B-frags: W2 as bf16, named regs. k = tap*8 + ic; lane(hi,lo):
    // B[k=kk*32+hi*8+j][n=lo] -> tap = kk*4+hi, ic=j. tap>=9 => 0 (K-pad).
    #define MK_WB(KK) ({                                                    \
        bf16x8 v_;                                                          \
        const int tap_ = (KK) * 4 + hi;                                     \
        _Pragma("unroll")                                                   \
        for (int j = 0; j < 8; j++)                                         \
            v_[j] = (tap_ < 9) ? f2bf(W2[lo * 72 + j * 9 + tap_])           \
                               : (short)0;                                  \
        v_; })
    const bf16x8 wb0 = MK_WB(0), wb1 = MK_WB(1), wb2 = MK_WB(2);

    // conv2 A-read byte offsets into sz1[w]: slot = (2qy+ty)*19 + (2qx+tx)
    #define MK_POSOFF(T) ({                                                 \
        int p_ = (T) * 16 + lo; if (p_ > 48) p_ = 48;                       \
        int qy_ = p_ / 7, qx_ = p_ - qy_ * 7;                               \
        ((2 * qy_) * Z1_RS + 2 * qx_) * 16; })
    const int posoff0 = MK_POSOFF(0), posoff1 = MK_POSOFF(1),
              posoff2 = MK_POSOFF(2), posoff3 = MK_POSOFF(3);
    #define MK_TAPOFF(KK) ({                                                \
        int tap_ = (KK) * 4 + hi;                                           \
        int ty_ = tap_ / 3, tx_ = tap_ - ty_ * 3;                           \
        (tap_ < 9) ? (ty_ * Z1_RS + tx_) * 16 : 0; })
    const int tapoff0 = MK_TAPOFF(0), tapoff1 = MK_TAPOFF(1),
              tapoff2 = MK_TAPOFF(2);

    // Epilogue constants: lane(hi,lo) holds D[pos=t*16+hi*4+r][c2=lo].
    const float b2v = b2[lo];
    #define MK_WFC(T) ({                                                    \
        f32x4 v_;                                                           \
        _Pragma("unroll")                                                   \
        for (int r = 0; r < 4; r++) {                                       \
            int p_ = (T) * 16 + hi * 4 + r;                                 \
            v_[r] = (p_ < 49) ? Wfc[lo * 49 + p_] : 0.f;                    \
        }                                                                   \
        v_; })
    const f32x4 wfct0 = MK_WFC(0), wfct1 = MK_WFC(1),
                wfct2 = MK_WFC(2), wfct3 = MK_WFC(3);
    const float bfc0 = bfc[0];

    const int nquad = (nimg + 3) >> 2;
    char* const z1b = (char*)&sz1[w][0];

    for (int q = blockIdx.x; q < nquad; q += gridDim.x) {
        int img = q * 4 + w;
        if (img >= nimg) img = nimg - 1;
        const float* __restrict__ xi = x + (size_t)img * 784;

        // ---- conv1 (fp32 VALU), taps direct from global (L1/L2-resident) ----
        CONV1_STEP(0, 1);
        CONV1_STEP(1, 1);
        CONV1_STEP(2, 1);
        CONV1_STEP(3, lane < 4);

        // ---- conv2: 4 pos-tiles x 3 K-steps; A = z1 (one b128/frag) ----
        f32x4 acc0 = {0.f, 0.f, 0.f, 0.f};
        f32x4 acc1 = {0.f, 0.f, 0.f, 0.f};
        f32x4 acc2 = {0.f, 0.f, 0.f, 0.f};
        f32x4 acc3 = {0.f, 0.f, 0.f, 0.f};
        #define C2(ACC, POS) do {                                           \
            ACC = __builtin_amdgcn_mfma_f32_16x16x32_bf16(                  \
                *(const bf16x8*)(z1b + (POS) + tapoff0), wb0, ACC, 0, 0, 0);\
            ACC = __builtin_amdgcn_mfma_f32_16x16x32_bf16(                  \
                *(const bf16x8*)(z1b + (POS) + tapoff1), wb1, ACC, 0, 0, 0);\
            ACC = __builtin_amdgcn_mfma_f32_16x16x32_bf16(                  \
                *(const bf16x8*)(z1b + (POS) + tapoff2), wb2, ACC, 0, 0, 0);\
        } while (0)
        C2(acc0, posoff0);
        C2(acc1, posoff1);
        C2(acc2, posoff2);
        C2(acc3, posoff3);

        // ---- epilogue: bias+ReLU+FC fold, wave reduce, softplus ----
        float fc = 0.f;
        #define EPI(ACC, WF) do {                                           \
            _Pragma("unroll")                                               \
            for (int r = 0; r < 4; r++) {                                   \
                float z_ = fmaxf((ACC)[r] + b2v, 0.f);                      \
                fc = fmaf(z_, (WF)[r], fc);                                 \
            }                                                               \
        } while (0)
        EPI(acc0, wfct0);
        EPI(acc1, wfct1);
        EPI(acc2, wfct2);
        EPI(acc3, wfct3);
        #pragma unroll
        for (int off = 32; off > 0; off >>= 1)
            fc += __shfl_down(fc, off, 64);

        if (lane == 0) {
            int imgo = q * 4 + w;
            if (imgo < nimg) {
                float v    = fc + bfc0;
                float sp   = fmaxf(v, 0.f) + log1pf(expf(-fabsf(v)));
                float rate = sp + 0.001f;
                float pr   = 1.f - expf(-rate);
                out[imgo] = fminf(fmaxf(pr, 1e-6f), 1.f - 1e-6f);
            }
        }
    }
}

extern "C" void kernel_launch(void* const* d_in, const int* in_sizes, int n_in,
                              void* d_out, int out_size, void* d_ws, size_t ws_size,
                              hipStream_t stream) {
    const float* x   = (const float*)d_in[0];
    const float* W1  = (const float*)d_in[1];
    const float* b1  = (const float*)d_in[2];
    const float* W2  = (const float*)d_in[3];
    const float* b2  = (const float*)d_in[4];
    const float* Wfc = (const float*)d_in[5];
    const float* bfc = (const float*)d_in[6];
    float* out = (float*)d_out;

    const int nimg  = in_sizes[0] / 784;
    const int nquad = (nimg + 3) / 4;
    const int grid  = nquad < NBLOCKS ? nquad : NBLOCKS;

    fused_cnn_mfma<<<grid, 256, 0, stream>>>(x, W1, b1, W2, b2, Wfc, bfc,
                                             out, nimg);
}

// Round 14
// 448.030 us; speedup vs baseline: 1.1000x; 1.1000x over previous
//
#include <hip/hip_runtime.h>
#include <math.h>

// Fused CNN classifier: conv(1->8,3x3,s2,p1)+ReLU -> conv(8->16,3x3,s2,p1)+ReLU
//                       -> FC(784->1) -> softplus+0.001 -> 1-exp(-r) -> clip
// B=65536 images of 1x28x28 fp32.
//
// R13 (resubmit — R13 bench was a GPUAcquisitionTimeout, no data):
// batch-2 ILP (pre-registered R12 fallback). R12 confirmed: bounds>4
// forces <=64-VGPR budget (HW waves/EU halves at 64/128) -> allocator
// spills (VGPR 32, WRITE 220MB, dur 293us). Occupancy DOES track the
// bounds declaration (4/6/8 -> 40/63/88%) but can't be bought with spill.
// So buy latency-hiding with ILP instead: each wave processes TWO images
// per iteration, step-interleaved (A0,B0,A1,B1,...): B's 24 global tap
// loads fly under A's FMA chain; 8 independent MFMA chains; 2 interleaved
// shfl reduces. Same latency-hiding product as 2x waves, paid in VGPRs
// we have (peak ~85 < 128 at bounds4, no spill). LDS: sz1 x2 = 36.5KB.
// Predicted: dur 137.6 -> 85-105us, VGPR 80-105, WRITE ~0.5MB, occ ~40%,
// FETCH ~100MB. Flat dur => shared-pipe (L1 taps) => re-stage image in LDS.

typedef short bf16x8 __attribute__((ext_vector_type(8)));
typedef float f32x4  __attribute__((ext_vector_type(4)));

#define NBLOCKS 4096
#define Z1_RS 19                    // z1 row stride in 16B slots (odd!)
#define Z1_SLOTS (15 * Z1_RS)       // 285 slots per image

static __device__ __forceinline__ short f2bf(float f) {
    union { float f; unsigned u; } v; v.f = f;
    unsigned r = v.u + 0x7FFF + ((v.u >> 16) & 1);   // RNE (no NaN inputs)
    return (short)(r >> 16);
}

// One conv1 channel pair (CA, CA+1): 9-tap FMA + ReLU + pack to 2xbf16.
#define CONV1_PAIR(CA, PKDST) do {                                          \
    const float* wa_ = &W1[(CA) * 9];                                       \
    const float* wc_ = &W1[((CA) + 1) * 9];                                 \
    float za_ = b1[(CA)], zc_ = b1[(CA) + 1];                               \
    za_ = fmaf(t0, wa_[0], za_); zc_ = fmaf(t0, wc_[0], zc_);               \
    za_ = fmaf(t1, wa_[1], za_); zc_ = fmaf(t1, wc_[1], zc_);               \
    za_ = fmaf(t2, wa_[2], za_); zc_ = fmaf(t2, wc_[2], zc_);               \
    za_ = fmaf(t3, wa_[3], za_); zc_ = fmaf(t3, wc_[3], zc_);               \
    za_ = fmaf(t4, wa_[4], za_); zc_ = fmaf(t4, wc_[4], zc_);               \
    za_ = fmaf(t5, wa_[5], za_); zc_ = fmaf(t5, wc_[5], zc_);               \
    za_ = fmaf(t6, wa_[6], za_); zc_ = fmaf(t6, wc_[6], zc_);               \
    za_ = fmaf(t7, wa_[7], za_); zc_ = fmaf(t7, wc_[7], zc_);               \
    za_ = fmaf(t8, wa_[8], za_); zc_ = fmaf(t8, wc_[8], zc_);               \
    za_ = fmaxf(za_, 0.f);       zc_ = fmaxf(zc_, 0.f);                     \
    asm("v_cvt_pk_bf16_f32 %0, %1, %2" : "=v"(PKDST) : "v"(za_), "v"(zc_)); \
} while (0)

// One conv1 output position for image XI -> z1 buffer Z1B.
// Output pos (py,px) reads input rows 2py-1..2py+1, cols 2px-1..2px+1;
// row -1 / col -1 are pad-zeros: clamp the address, zero via 0/1 masks.
#define CONV1_STEP(I, XI, Z1B, STORE_COND) do {                               \
    int p_ = (I) * 64 + lane; if (p_ > 195) p_ = 195;                         \
    int py_ = p_ / 14, px_ = p_ - py_ * 14;                                   \
    int r1_ = py_ * 56;                 /* (2py)*28   */                      \
    int r0_ = r1_ - 28; if (r0_ < 0) r0_ = 0;                                 \
    int r2_ = r1_ + 28;                                                       \
    int c1_ = px_ * 2;                                                        \
    int c0_ = c1_ - 1; if (c0_ < 0) c0_ = 0;                                  \
    float mt_  = (py_ > 0) ? 1.f : 0.f;                                       \
    float ml_  = (px_ > 0) ? 1.f : 0.f;                                       \
    float mtl_ = mt_ * ml_;                                                   \
    float2 a12 = *(const float2*)((XI) + r0_ + c1_);   /* 8B-aligned */       \
    float  a0  = (XI)[r0_ + c0_];                                             \
    float2 b45 = *(const float2*)((XI) + r1_ + c1_);                          \
    float  b3  = (XI)[r1_ + c0_];                                             \
    float2 c78 = *(const float2*)((XI) + r2_ + c1_);                          \
    float  c6  = (XI)[r2_ + c0_];                                             \
    float t0 = a0 * mtl_, t1 = a12.x * mt_, t2 = a12.y * mt_;                 \
    float t3 = b3 * ml_,  t4 = b45.x,       t5 = b45.y;                       \
    float t6 = c6 * ml_,  t7 = c78.x,       t8 = c78.y;                       \
    asm volatile("" : "+v"(t0), "+v"(t1), "+v"(t2), "+v"(t3), "+v"(t4),       \
                      "+v"(t5), "+v"(t6), "+v"(t7), "+v"(t8));                \
    unsigned pk0_, pk1_, pk2_, pk3_;                                          \
    CONV1_PAIR(0, pk0_);                                                      \
    CONV1_PAIR(2, pk1_);                                                      \
    CONV1_PAIR(4, pk2_);                                                      \
    CONV1_PAIR(6, pk3_);                                                      \
    int zoff_ = ((py_ + 1) * Z1_RS + px_ + 1) * 16;                           \
    if (STORE_COND)                                                           \
        *(uint4*)((Z1B) + zoff_) = make_uint4(pk0_, pk1_, pk2_, pk3_);        \
} while (0)

__global__ __launch_bounds__(256, 4) void fused_cnn_mfma(
    const float* __restrict__ x,
    const float* __restrict__ W1, const float* __restrict__ b1,
    const float* __restrict__ W2, const float* __restrict__ b2,
    const float* __restrict__ Wfc, const float* __restrict__ bfc,
    float* __restrict__ out, int nimg)
{
    __shared__ bf16x8 sz1[8][Z1_SLOTS];     // 36480 B: slots w (A), w+4 (B)

    const int tid  = threadIdx.x;
    const int w    = tid >> 6;       // wave id (wave-private LDS, no barriers)
    const int lane = tid & 63;
    const int hi   = lane >> 4;
    const int lo   = lane & 15;

    // ---------------- one-time setup (all wave-private, no barrier) --------
    {
        bf16x8 zz = {0,0,0,0,0,0,0,0};
        for (int i = lane; i < Z1_SLOTS; i += 64) {
            sz1[w][i]     = zz;
            sz1[w + 4][i] = zz;
        }
    }

    // B-frags: W2 as bf16, named regs. k = tap*8 + ic; lane(hi,lo):
    // B[k=kk*32+hi*8+j][n=lo] -> tap = kk*4+hi, ic=j. tap>=9 => 0 (K-pad).
    #define MK_WB(KK) ({                                                    \
        bf16x8 v_;                                                          \
        const int tap_ = (KK) * 4 + hi;                                     \
        _Pragma("unroll")                                                   \
        for (int j = 0; j < 8; j++)                                         \
            v_[j] = (tap_ < 9) ? f2bf(W2[lo * 72 + j * 9 + tap_])           \
                               : (short)0;                                  \
        v_; })
    const bf16x8 wb0 = MK_WB(0), wb1 = MK_WB(1), wb2 = MK_WB(2);

    // conv2 A-read byte offsets into sz1: slot = (2qy+ty)*19 + (2qx+tx)
    #define MK_POSOFF(T) ({                                                 \
        int p_ = (T) * 16 + lo; if (p_ > 48) p_ = 48;                       \
        int qy_ = p_ / 7, qx_ = p_ - qy_ * 7;                               \
        ((2 * qy_) * Z1_RS + 2 * qx_) * 16; })
    const int posoff0 = MK_POSOFF(0), posoff1 = MK_POSOFF(1),
              posoff2 = MK_POSOFF(2), posoff3 = MK_POSOFF(3);
    #define MK_TAPOFF(KK) ({                                                \
        int tap_ = (KK) * 4 + hi;                                           \
        int ty_ = tap_ / 3, tx_ = tap_ - ty_ * 3;                           \
        (tap_ < 9) ? (ty_ * Z1_RS + tx_) * 16 : 0; })
    const int tapoff0 = MK_TAPOFF(0), tapoff1 = MK_TAPOFF(1),
              tapoff2 = MK_TAPOFF(2);

    // Epilogue constants: lane(hi,lo) holds D[pos=t*16+hi*4+r][c2=lo].
    const float b2v = b2[lo];
    #define MK_WFC(T) ({                                                    \
        f32x4 v_;                                                           \
        _Pragma("unroll")                                                   \
        for (int r = 0; r < 4; r++) {                                       \
            int p_ = (T) * 16 + hi * 4 + r;                                 \
            v_[r] = (p_ < 49) ? Wfc[lo * 49 + p_] : 0.f;                    \
        }                                                                   \
        v_; })
    const f32x4 wfct0 = MK_WFC(0), wfct1 = MK_WFC(1),
                wfct2 = MK_WFC(2), wfct3 = MK_WFC(3);
    const float bfc0 = bfc[0];

    const int noct = (nimg + 7) >> 3;
    char* const z1bA = (char*)&sz1[w][0];
    char* const z1bB = (char*)&sz1[w + 4][0];

    for (int o = blockIdx.x; o < noct; o += gridDim.x) {
        int imgA = o * 8 + w;
        int imgB = o * 8 + 4 + w;
        int imgAc = imgA < nimg ? imgA : nimg - 1;
        int imgBc = imgB < nimg ? imgB : nimg - 1;
        const float* __restrict__ xiA = x + (size_t)imgAc * 784;
        const float* __restrict__ xiB = x + (size_t)imgBc * 784;

        // ---- conv1 x2, step-interleaved: B's loads fly under A's FMAs ----
        CONV1_STEP(0, xiA, z1bA, 1);
        CONV1_STEP(0, xiB, z1bB, 1);
        CONV1_STEP(1, xiA, z1bA, 1);
        CONV1_STEP(1, xiB, z1bB, 1);
        CONV1_STEP(2, xiA, z1bA, 1);
        CONV1_STEP(2, xiB, z1bB, 1);
        CONV1_STEP(3, xiA, z1bA, lane < 4);
        CONV1_STEP(3, xiB, z1bB, lane < 4);

        // ---- conv2 x2: 8 independent MFMA chains, interleaved ----
        f32x4 accA0 = {0.f,0.f,0.f,0.f}, accA1 = {0.f,0.f,0.f,0.f};
        f32x4 accA2 = {0.f,0.f,0.f,0.f}, accA3 = {0.f,0.f,0.f,0.f};
        f32x4 accB0 = {0.f,0.f,0.f,0.f}, accB1 = {0.f,0.f,0.f,0.f};
        f32x4 accB2 = {0.f,0.f,0.f,0.f}, accB3 = {0.f,0.f,0.f,0.f};
        #define C2(ACC, Z1B, POS) do {                                      \
            ACC = __builtin_amdgcn_mfma_f32_16x16x32_bf16(                  \
                *(const bf16x8*)((Z1B) + (POS) + tapoff0), wb0, ACC, 0,0,0);\
            ACC = __builtin_amdgcn_mfma_f32_16x16x32_bf16(                  \
                *(const bf16x8*)((Z1B) + (POS) + tapoff1), wb1, ACC, 0,0,0);\
            ACC = __builtin_amdgcn_mfma_f32_16x16x32_bf16(                  \
                *(const bf16x8*)((Z1B) + (POS) + tapoff2), wb2, ACC, 0,0,0);\
        } while (0)
        C2(accA0, z1bA, posoff0);
        C2(accB0, z1bB, posoff0);
        C2(accA1, z1bA, posoff1);
        C2(accB1, z1bB, posoff1);
        C2(accA2, z1bA, posoff2);
        C2(accB2, z1bB, posoff2);
        C2(accA3, z1bA, posoff3);
        C2(accB3, z1bB, posoff3);

        // ---- epilogue x2: bias+ReLU+FC fold, two interleaved reduces ----
        float fcA = 0.f, fcB = 0.f;
        #define EPI(FC, ACC, WF) do {                                       \
            _Pragma("unroll")                                               \
            for (int r = 0; r < 4; r++) {                                   \
                float z_ = fmaxf((ACC)[r] + b2v, 0.f);                      \
                FC = fmaf(z_, (WF)[r], FC);                                 \
            }                                                               \
        } while (0)
        EPI(fcA, accA0, wfct0); EPI(fcB, accB0, wfct0);
        EPI(fcA, accA1, wfct1); EPI(fcB, accB1, wfct1);
        EPI(fcA, accA2, wfct2); EPI(fcB, accB2, wfct2);
        EPI(fcA, accA3, wfct3); EPI(fcB, accB3, wfct3);
        #pragma unroll
        for (int off = 32; off > 0; off >>= 1) {
            fcA += __shfl_down(fcA, off, 64);
            fcB += __shfl_down(fcB, off, 64);
        }

        if (lane == 0) {
            #define FINISH(FC, IMG) do {                                    \
                if ((IMG) < nimg) {                                         \
                    float v_    = (FC) + bfc0;                              \
                    float sp_   = fmaxf(v_, 0.f) + log1pf(expf(-fabsf(v_)));\
                    float rate_ = sp_ + 0.001f;                             \
                    float pr_   = 1.f - expf(-rate_);                       \
                    out[(IMG)] = fminf(fmaxf(pr_, 1e-6f), 1.f - 1e-6f);     \
                }                                                           \
            } while (0)
            FINISH(fcA, imgA);
            FINISH(fcB, imgB);
        }
    }
}

extern "C" void kernel_launch(void* const* d_in, const int* in_sizes, int n_in,
                              void* d_out, int out_size, void* d_ws, size_t ws_size,
                              hipStream_t stream) {
    const float* x   = (const float*)d_in[0];
    const float* W1  = (const float*)d_in[1];
    const float* b1  = (const float*)d_in[2];
    const float* W2  = (const float*)d_in[3];
    const float* b2  = (const float*)d_in[4];
    const float* Wfc = (const float*)d_in[5];
    const float* bfc = (const float*)d_in[6];
    float* out = (float*)d_out;

    const int nimg = in_sizes[0] / 784;
    const int noct = (nimg + 7) / 8;
    const int grid = noct < NBLOCKS ? noct : NBLOCKS;

    fused_cnn_mfma<<<grid, 256, 0, stream>>>(x, W1, b1, W2, b2, Wfc, bfc,
                                             out, nimg);
}

// Round 15
// 345.904 us; speedup vs baseline: 1.4247x; 1.2952x over previous
//
#include <hip/hip_runtime.h>
#include <math.h>

// Fused CNN classifier: conv(1->8,3x3,s2,p1)+ReLU -> conv(8->16,3x3,s2,p1)+ReLU
//                       -> FC(784->1) -> softplus+0.001 -> 1-exp(-r) -> clip
// B=65536 images of 1x28x28 fp32.
//
// R14: 5-wave occupancy experiment on the R9 (best, ~114.5us) structure.
// Allocator law from R10/R11/R12/R13: with MFMA, arch-VGPR budget =
// (512/waves_per_eu)/2 (accum_offset splits the file): bounds 4/6/8 ->
// arch 64/40/32, and exceeding it spills (R13: batch-2 at bounds4, VGPR
// pegged 64, WRITE 125MB, 245us). So TLP needs arch <= ~51 and LDS <= 32KB:
//  - simg stored LINEAR (784 floats, 12.5KB/4 imgs): staging = sp4[lane]=pf,
//    borders via R13's mask logic reading LDS (R9-style LDS taps, which beat
//    R11's direct-global taps by 20%).
//  - wfct NOT persistent: 13 loads from L1-resident Wfc after conv1 ->
//    conv1-phase peak pressure -16 regs.
//  - __launch_bounds__(256,5); LDS 30.8KB -> 5 blocks/CU.
// Predicted (a) success: VGPR 56-72, WRITE ~0.5MB, occ ~50%, dur 90-110us;
// (b) spill (VGPR ~48-52, WRITE >10MB): half-budget law confirmed -> next
// round bounds(256,4) + v_pk_fma chain trim.

typedef short bf16x8 __attribute__((ext_vector_type(8)));
typedef float f32x4  __attribute__((ext_vector_type(4)));

#define NBLOCKS 4096
#define Z1_RS 19                    // z1 row stride in 16B slots (odd!)
#define Z1_SLOTS (15 * Z1_RS)       // 285 slots per image

static __device__ __forceinline__ short f2bf(float f) {
    union { float f; unsigned u; } v; v.f = f;
    unsigned r = v.u + 0x7FFF + ((v.u >> 16) & 1);   // RNE (no NaN inputs)
    return (short)(r >> 16);
}

// One conv1 channel pair (CA, CA+1): 9-tap FMA + ReLU + pack to 2xbf16.
#define CONV1_PAIR(CA, PKDST) do {                                          \
    const float* wa_ = &W1[(CA) * 9];                                       \
    const float* wc_ = &W1[((CA) + 1) * 9];                                 \
    float za_ = b1[(CA)], zc_ = b1[(CA) + 1];                               \
    za_ = fmaf(t0, wa_[0], za_); zc_ = fmaf(t0, wc_[0], zc_);               \
    za_ = fmaf(t1, wa_[1], za_); zc_ = fmaf(t1, wc_[1], zc_);               \
    za_ = fmaf(t2, wa_[2], za_); zc_ = fmaf(t2, wc_[2], zc_);               \
    za_ = fmaf(t3, wa_[3], za_); zc_ = fmaf(t3, wc_[3], zc_);               \
    za_ = fmaf(t4, wa_[4], za_); zc_ = fmaf(t4, wc_[4], zc_);               \
    za_ = fmaf(t5, wa_[5], za_); zc_ = fmaf(t5, wc_[5], zc_);               \
    za_ = fmaf(t6, wa_[6], za_); zc_ = fmaf(t6, wc_[6], zc_);               \
    za_ = fmaf(t7, wa_[7], za_); zc_ = fmaf(t7, wc_[7], zc_);               \
    za_ = fmaf(t8, wa_[8], za_); zc_ = fmaf(t8, wc_[8], zc_);               \
    za_ = fmaxf(za_, 0.f);       zc_ = fmaxf(zc_, 0.f);                     \
    asm("v_cvt_pk_bf16_f32 %0, %1, %2" : "=v"(PKDST) : "v"(za_), "v"(zc_)); \
} while (0)

// One conv1 output position, taps read from the LINEAR image XI (LDS).
// Output pos (py,px) reads input rows 2py-1..2py+1, cols 2px-1..2px+1;
// row -1 / col -1 are pad-zeros: clamp the address, zero via 0/1 masks.
#define CONV1_STEP(I, XI, Z1B, STORE_COND) do {                               \
    int p_ = (I) * 64 + lane; if (p_ > 195) p_ = 195;                         \
    int py_ = p_ / 14, px_ = p_ - py_ * 14;                                   \
    int r1_ = py_ * 56;                 /* (2py)*28   */                      \
    int r0_ = r1_ - 28; if (r0_ < 0) r0_ = 0;                                 \
    int r2_ = r1_ + 28;                                                       \
    int c1_ = px_ * 2;                                                        \
    int c0_ = c1_ - 1; if (c0_ < 0) c0_ = 0;                                  \
    float mt_  = (py_ > 0) ? 1.f : 0.f;                                       \
    float ml_  = (px_ > 0) ? 1.f : 0.f;                                       \
    float mtl_ = mt_ * ml_;                                                   \
    float2 a12 = *(const float2*)((XI) + r0_ + c1_);   /* 8B-aligned */       \
    float  a0  = (XI)[r0_ + c0_];                                             \
    float2 b45 = *(const float2*)((XI) + r1_ + c1_);                          \
    float  b3  = (XI)[r1_ + c0_];                                             \
    float2 c78 = *(const float2*)((XI) + r2_ + c1_);                          \
    float  c6  = (XI)[r2_ + c0_];                                             \
    float t0 = a0 * mtl_, t1 = a12.x * mt_, t2 = a12.y * mt_;                 \
    float t3 = b3 * ml_,  t4 = b45.x,       t5 = b45.y;                       \
    float t6 = c6 * ml_,  t7 = c78.x,       t8 = c78.y;                       \
    asm volatile("" : "+v"(t0), "+v"(t1), "+v"(t2), "+v"(t3), "+v"(t4),       \
                      "+v"(t5), "+v"(t6), "+v"(t7), "+v"(t8));                \
    unsigned pk0_, pk1_, pk2_, pk3_;                                          \
    CONV1_PAIR(0, pk0_);                                                      \
    CONV1_PAIR(2, pk1_);                                                      \
    CONV1_PAIR(4, pk2_);                                                      \
    CONV1_PAIR(6, pk3_);                                                      \
    int zoff_ = ((py_ + 1) * Z1_RS + px_ + 1) * 16;                           \
    if (STORE_COND)                                                           \
        *(uint4*)((Z1B) + zoff_) = make_uint4(pk0_, pk1_, pk2_, pk3_);        \
} while (0)

__global__ __launch_bounds__(256, 5) void fused_cnn_mfma(
    const float* __restrict__ x,
    const float* __restrict__ W1, const float* __restrict__ b1,
    const float* __restrict__ W2, const float* __restrict__ b2,
    const float* __restrict__ Wfc, const float* __restrict__ bfc,
    float* __restrict__ out, int nimg)
{
    __shared__ __align__(16) float simg[4][784];   // linear, 12544 B
    __shared__ bf16x8 sz1[4][Z1_SLOTS];            // 18240 B  (total 30784)

    const int tid  = threadIdx.x;
    const int w    = tid >> 6;       // wave id (wave-private LDS, no barriers)
    const int lane = tid & 63;
    const int hi   = lane >> 4;
    const int lo   = lane & 15;

    // ---- one-time: zero sz1 (pad ring must stay 0); simg fully overwritten
    {
        bf16x8 zz = {0,0,0,0,0,0,0,0};
        for (int i = lane; i < Z1_SLOTS; i += 64) sz1[w][i] = zz;
    }

    // B-frags: W2 as bf16, named regs. k = tap*8 + ic; lane(hi,lo):
    // B[k=kk*32+hi*8+j][n=lo] -> tap = kk*4+hi, ic=j. tap>=9 => 0 (K-pad).
    #define MK_WB(KK) ({                                                    \
        bf16x8 v_;                                                          \
        const int tap_ = (KK) * 4 + hi;                                     \
        _Pragma("unroll")                                                   \
        for (int j = 0; j < 8; j++)                                         \
            v_[j] = (tap_ < 9) ? f2bf(W2[lo * 72 + j * 9 + tap_])           \
                               : (short)0;                                  \
        v_; })
    const bf16x8 wb0 = MK_WB(0), wb1 = MK_WB(1), wb2 = MK_WB(2);

    // conv2 A-read byte offsets into sz1: slot = (2qy+ty)*19 + (2qx+tx)
    #define MK_POSOFF(T) ({                                                 \
        int p_ = (T) * 16 + lo; if (p_ > 48) p_ = 48;                       \
        int qy_ = p_ / 7, qx_ = p_ - qy_ * 7;                               \
        ((2 * qy_) * Z1_RS + 2 * qx_) * 16; })
    const int posoff0 = MK_POSOFF(0), posoff1 = MK_POSOFF(1),
              posoff2 = MK_POSOFF(2), posoff3 = MK_POSOFF(3);
    #define MK_TAPOFF(KK) ({                                                \
        int tap_ = (KK) * 4 + hi;                                           \
        int ty_ = tap_ / 3, tx_ = tap_ - ty_ * 3;                           \
        (tap_ < 9) ? (ty_ * Z1_RS + tx_) * 16 : 0; })
    const int tapoff0 = MK_TAPOFF(0), tapoff1 = MK_TAPOFF(1),
              tapoff2 = MK_TAPOFF(2);

    const float b2v  = b2[lo];
    const float bfc0 = bfc[0];
    // wfct NOT kept in registers: loaded per-iteration after conv1 (L1-hit).
    const float* const wfp = Wfc + lo * 49 + hi * 4;   // base for t*16 + r

    const int nquad = (nimg + 3) >> 2;
    float* const si  = &simg[w][0];
    char*  const z1b = (char*)&sz1[w][0];

    // ---- prologue prefetch: image for q = blockIdx.x ----
    float4 pf0, pf1, pf2, pf3;
    {
        int img = blockIdx.x * 4 + w;
        if (img >= nimg) img = nimg - 1;
        const float4* sp = (const float4*)(x + (size_t)img * 784);
        int l3 = lane < 4 ? lane : 0;
        pf0 = sp[lane]; pf1 = sp[64 + lane]; pf2 = sp[128 + lane];
        pf3 = sp[192 + l3];
    }

    for (int q = blockIdx.x; q < nquad; q += gridDim.x) {
        // ---- stage prefetched image (linear, trivially coalesced) ----
        {
            float4* sp4 = (float4*)si;
            sp4[lane]       = pf0;
            sp4[64 + lane]  = pf1;
            sp4[128 + lane] = pf2;
            if (lane < 4) sp4[192 + lane] = pf3;
        }

        // ---- issue next image's loads; complete under conv1+conv2 ----
        {
            int qn = q + gridDim.x;
            if (qn < nquad) {
                int imgn = qn * 4 + w;
                if (imgn >= nimg) imgn = nimg - 1;
                const float4* sp = (const float4*)(x + (size_t)imgn * 784);
                int l3 = lane < 4 ? lane : 0;
                pf0 = sp[lane]; pf1 = sp[64 + lane]; pf2 = sp[128 + lane];
                pf3 = sp[192 + l3];
            }
        }

        // ---- conv1 (fp32 VALU), taps from LDS with border masks ----
        CONV1_STEP(0, si, z1b, 1);
        CONV1_STEP(1, si, z1b, 1);
        CONV1_STEP(2, si, z1b, 1);
        CONV1_STEP(3, si, z1b, lane < 4);

        // ---- wfct loads (L1-resident Wfc), issued before conv2 waits ----
        float wf00 = wfp[0],  wf01 = wfp[1],  wf02 = wfp[2],  wf03 = wfp[3];
        float wf10 = wfp[16], wf11 = wfp[17], wf12 = wfp[18], wf13 = wfp[19];
        float wf20 = wfp[32], wf21 = wfp[33], wf22 = wfp[34], wf23 = wfp[35];
        float wf30 = 0.f;
        if (hi == 0) wf30 = wfp[48];          // only p=48 is valid in tile 3

        // ---- conv2: 4 pos-tiles x 3 K-steps; A = z1 (one b128/frag) ----
        f32x4 acc0 = {0.f,0.f,0.f,0.f}, acc1 = {0.f,0.f,0.f,0.f};
        f32x4 acc2 = {0.f,0.f,0.f,0.f}, acc3 = {0.f,0.f,0.f,0.f};
        #define C2(ACC, POS) do {                                           \
            ACC = __builtin_amdgcn_mfma_f32_16x16x32_bf16(                  \
                *(const bf16x8*)(z1b + (POS) + tapoff0), wb0, ACC, 0,0,0);  \
            ACC = __builtin_amdgcn_mfma_f32_16x16x32_bf16(                  \
                *(const bf16x8*)(z1b + (POS) + tapoff1), wb1, ACC, 0,0,0);  \
            ACC = __builtin_amdgcn_mfma_f32_16x16x32_bf16(                  \
                *(const bf16x8*)(z1b + (POS) + tapoff2), wb2, ACC, 0,0,0);  \
        } while (0)
        C2(acc0, posoff0);
        C2(acc1, posoff1);
        C2(acc2, posoff2);
        C2(acc3, posoff3);

        // ---- epilogue: bias+ReLU+FC fold, wave reduce, softplus ----
        float fc = 0.f;
        #define EPI1(ACCR, WF) fc = fmaf(fmaxf((ACCR) + b2v, 0.f), (WF), fc)
        EPI1(acc0[0], wf00); EPI1(acc0[1], wf01);
        EPI1(acc0[2], wf02); EPI1(acc0[3], wf03);
        EPI1(acc1[0], wf10); EPI1(acc1[1], wf11);
        EPI1(acc1[2], wf12); EPI1(acc1[3], wf13);
        EPI1(acc2[0], wf20); EPI1(acc2[1], wf21);
        EPI1(acc2[2], wf22); EPI1(acc2[3], wf23);
        EPI1(acc3[0], wf30);
        #pragma unroll
        for (int off = 32; off > 0; off >>= 1)
            fc += __shfl_down(fc, off, 64);

        if (lane == 0) {
            int imgo = q * 4 + w;
            if (imgo < nimg) {
                float v    = fc + bfc0;
                float sp   = fmaxf(v, 0.f) + log1pf(expf(-fabsf(v)));
                float rate = sp + 0.001f;
                float pr   = 1.f - expf(-rate);
                out[imgo] = fminf(fmaxf(pr, 1e-6f), 1.f - 1e-6f);
            }
        }
    }
}

extern "C" void kernel_launch(void* const* d_in, const int* in_sizes, int n_in,
                              void* d_out, int out_size, void* d_ws, size_t ws_size,
                              hipStream_t stream) {
    const float* x   = (const float*)d_in[0];
    const float* W1  = (const float*)d_in[1];
    const float* b1  = (const float*)d_in[2];
    const float* W2  = (const float*)d_in[3];
    const float* b2  = (const float*)d_in[4];
    const float* Wfc = (const float*)d_in[5];
    const float* bfc = (const float*)d_in[6];
    float* out = (float*)d_out;

    const int nimg  = in_sizes[0] / 784;
    const int nquad = (nimg + 3) / 4;
    const int grid  = nquad < NBLOCKS ? nquad : NBLOCKS;

    fused_cnn_mfma<<<grid, 256, 0, stream>>>(x, W1, b1, W2, b2, Wfc, bfc,
                                             out, nimg);
}